// Round 5
// baseline (990.048 us; speedup 1.0000x reference)
//
#include <hip/hip_runtime.h>
#include <cstdint>
#include <cstddef>

typedef __attribute__((ext_vector_type(8))) short short8;
typedef __attribute__((ext_vector_type(4))) float floatx4;
typedef unsigned short u16;
typedef unsigned long long u64;

union FragAB { short8 s; u64 q[2]; };
struct L16 { u64 lo, hi; };

__device__ __forceinline__ float bf2f(u16 u) {
  union { unsigned int i; float f; } v; v.i = ((unsigned int)u) << 16; return v.f;
}
__device__ __forceinline__ u16 f2bf(float f) {
  union { float f; unsigned int u; } v; v.f = f;
  return (u16)((v.u + 0x7fffu + ((v.u >> 16) & 1u)) >> 16);
}
__device__ __forceinline__ void bfp(unsigned int p, float& x, float& y) {
  union { unsigned int i; float f; } a, b;
  a.i = p << 16; b.i = p & 0xffff0000u;
  x = a.f; y = b.f;
}
__device__ __forceinline__ unsigned int packbf(float a, float b) {
  return (unsigned int)f2bf(a) | ((unsigned int)f2bf(b) << 16);
}
__device__ __forceinline__ u64 pack4(float a, float b, float c, float d) {
  return (u64)f2bf(a) | ((u64)f2bf(b) << 16) | ((u64)f2bf(c) << 32) | ((u64)f2bf(d) << 48);
}

// ---------------- DCT-II orthonormal 56x56 matrix (fp32) ----------------
__global__ __launch_bounds__(256) void k_dctmat(float* __restrict__ Wd) {
  int i = blockIdx.x * 256 + threadIdx.x;
  if (i < 56 * 56) {
    int n = i / 56, x = i - n * 56;
    float v = cosf(3.14159265358979323846f * (float)n * ((float)x + 0.5f) / 56.0f)
              * 0.1889822365046136f;            // sqrt(2/56)
    if (n == 0) v *= 0.7071067811865476f;
    Wd[i] = v;
  }
}

// ---------------- depthwise conv 3x3, NCHW fp32 -> channel-last bf16 ----------------
__global__ __launch_bounds__(256) void k_conv(const float* __restrict__ x,
                                              const float* __restrict__ w9,
                                              const float* __restrict__ b1,
                                              u16* __restrict__ hbf) {
  __shared__ float xs[64 * 177];  // [c][3 rows][59 cols], col 0 <-> gx=-1
  const int y = blockIdx.x, c0 = blockIdx.y * 64, b = blockIdx.z;
  const int tid = threadIdx.x, cl = tid & 63, wv = tid >> 6;
  float wr[9];
  #pragma unroll
  for (int k = 0; k < 9; ++k) wr[k] = w9[(c0 + cl) * 9 + k];
  const float br = b1[c0 + cl];
  for (int it = 0; it < 48; ++it) {
    int combo = it * 4 + wv;             // 0..191 -> (c, r)
    int c = combo / 3, r = combo - c * 3;
    int col = tid & 63;
    if (col < 58) {
      int gy = y + r - 1, gx = col - 1;
      float v = 0.f;
      if (gy >= 0 && gy < 56 && gx >= 0 && gx < 56)
        v = x[(((size_t)b * 384 + c0 + c) * 56 + gy) * 56 + gx];
      xs[c * 177 + r * 59 + col] = v;
    }
  }
  __syncthreads();
  for (int it = 0; it < 14; ++it) {
    int px = it * 4 + wv;
    float a = br;
    #pragma unroll
    for (int dy = 0; dy < 3; ++dy)
      #pragma unroll
      for (int dx = 0; dx < 3; ++dx)
        a += wr[dy * 3 + dx] * xs[cl * 177 + dy * 59 + px + dx];
    hbf[((size_t)b * 3136 + y * 56 + px) * 384 + c0 + cl] = f2bf(a);
  }
}

// ---------------- one-pass GEMM: token-tile staged once, weight tiles looped ----------------
// Ts: 64 token-rows x 384 k, bf16, XOR-swizzled (chunk' = chunk ^ (row&7)), 49152 B.
// Ws: 128 weight-rows x 64 k, bf16, XOR-swizzled, 16384 B. Total LDS = 65536 B (2 blocks/CU).

__device__ __forceinline__ void stage_T_bf(const u16* __restrict__ A, int t0, u16* Ts) {
  const int tid = threadIdx.x;
  #pragma unroll
  for (int p = 0; p < 12; ++p) {
    int idx = p * 256 + tid;            // 3072 chunks of 8 u16
    int r = idx / 48, cc = idx - r * 48;
    L16 v = *(const L16*)(A + (size_t)(t0 + r) * 384 + cc * 8);
    int pb = r * 384 + ((cc ^ (r & 7)) << 3);
    *(u64*)&Ts[pb]     = v.lo;
    *(u64*)&Ts[pb + 4] = v.hi;
  }
}
__device__ __forceinline__ void stage_T_f32(const float* __restrict__ A, int t0, u16* Ts) {
  const int tid = threadIdx.x;
  #pragma unroll
  for (int p = 0; p < 12; ++p) {
    int idx = p * 256 + tid;
    int r = idx / 48, cc = idx - r * 48;
    const float4* s = (const float4*)(A + (size_t)(t0 + r) * 384 + cc * 8);
    float4 v0 = s[0], v1 = s[1];
    int pb = r * 384 + ((cc ^ (r & 7)) << 3);
    *(u64*)&Ts[pb]     = pack4(v0.x, v0.y, v0.z, v0.w);
    *(u64*)&Ts[pb + 4] = pack4(v1.x, v1.y, v1.z, v1.w);
  }
}
__device__ __forceinline__ void stage_W_f32(const float* __restrict__ W, int w0, int kt, u16* Ws) {
  const int tid = threadIdx.x;
  #pragma unroll
  for (int p = 0; p < 4; ++p) {
    int idx = p * 256 + tid;            // 1024 chunks
    int wr = idx >> 3, cb = idx & 7;
    const float4* s = (const float4*)(W + (size_t)(w0 + wr) * 384 + kt + cb * 8);
    float4 v0 = s[0], v1 = s[1];
    int pb = wr * 64 + ((cb ^ (wr & 7)) << 3);
    *(u64*)&Ws[pb]     = pack4(v0.x, v0.y, v0.z, v0.w);
    *(u64*)&Ws[pb + 4] = pack4(v1.x, v1.y, v1.z, v1.w);
  }
}
__device__ __forceinline__ void ldfragT(const u16* Ts, int tr, int kcol, FragAB& f) {
  int cc = kcol >> 3;
  int pb = tr * 384 + ((cc ^ (tr & 7)) << 3);
  f.q[0] = *(const u64*)&Ts[pb];
  f.q[1] = *(const u64*)&Ts[pb + 4];
}
__device__ __forceinline__ void ldfragW(const u16* Ws, int wr, int kcol, FragAB& f) {
  int cb = kcol >> 3;
  int pb = wr * 64 + ((cb ^ (wr & 7)) << 3);
  f.q[0] = *(const u64*)&Ws[pb];
  f.q[1] = *(const u64*)&Ws[pb + 4];
}

// GEMM1: h(bf16 tokens) @ lin_w^T(fp32) + lin_b -> xx (n<384), z (n>=384)
__global__ __launch_bounds__(256) void k_gemm_lin(const u16* __restrict__ A,
                                                  const float* __restrict__ Bw,
                                                  const float* __restrict__ bias,
                                                  u16* __restrict__ xx, u16* __restrict__ z) {
  __shared__ u16 Ts[64 * 384];
  __shared__ u16 Ws[128 * 64];
  const int tid = threadIdx.x, lane = tid & 63, wv = tid >> 6;
  const int wm = wv & 1, wn = wv >> 1, q = lane >> 4, l15 = lane & 15;
  const int t0 = blockIdx.x * 64;
  stage_T_bf(A, t0, Ts);
  for (int nt = 0; nt < 6; ++nt) {
    floatx4 acc[2][4];
    { floatx4 zv = {0.f, 0.f, 0.f, 0.f};
      #pragma unroll
      for (int i = 0; i < 2; ++i)
        #pragma unroll
        for (int j = 0; j < 4; ++j) acc[i][j] = zv; }
    for (int kt = 0; kt < 384; kt += 64) {
      __syncthreads();
      stage_W_f32(Bw, nt * 128, kt, Ws);
      __syncthreads();
      #pragma unroll
      for (int kc = 0; kc < 64; kc += 32) {
        FragAB af[2], bf[4];
        #pragma unroll
        for (int i = 0; i < 2; ++i) ldfragT(Ts, wm * 32 + i * 16 + l15, kt + kc + q * 8, af[i]);
        #pragma unroll
        for (int j = 0; j < 4; ++j) ldfragW(Ws, wn * 64 + j * 16 + l15, kc + q * 8, bf[j]);
        #pragma unroll
        for (int i = 0; i < 2; ++i)
          #pragma unroll
          for (int j = 0; j < 4; ++j)
            acc[i][j] = __builtin_amdgcn_mfma_f32_16x16x32_bf16(af[i].s, bf[j].s, acc[i][j], 0, 0, 0);
      }
    }
    #pragma unroll
    for (int i = 0; i < 2; ++i)
      #pragma unroll
      for (int j = 0; j < 4; ++j) {
        int ncol = nt * 128 + wn * 64 + j * 16 + l15;
        float bb = bias[ncol];
        u16* dst = (ncol < 384) ? (xx + ncol) : (z + (ncol - 384));
        #pragma unroll
        for (int r = 0; r < 4; ++r) {
          int t = t0 + wm * 32 + i * 16 + q * 4 + r;
          dst[(size_t)t * 384] = f2bf(acc[i][j][r] + bb);
        }
      }
  }
}

// GEMM2: freq_embed(fp32 tokens) @ tok_w^T(fp32) + tok_b -> gelu -> wave gain g (bf16)
__global__ __launch_bounds__(256) void k_gemm_tok(const float* __restrict__ A,
                                                  const float* __restrict__ Bw,
                                                  const float* __restrict__ bias,
                                                  const float* __restrict__ cs,
                                                  const float* __restrict__ al,
                                                  u16* __restrict__ g) {
  __shared__ u16 Ts[64 * 384];
  __shared__ u16 Ws[128 * 64];
  const int tid = threadIdx.x, lane = tid & 63, wv = tid >> 6;
  const int wm = wv & 1, wn = wv >> 1, q = lane >> 4, l15 = lane & 15;
  const int t0 = blockIdx.x * 64;
  const float c0 = cs[0], a0 = al[0];
  const float sc = (1.0f / (c0 + 1e-8f)) * (1.0f + 0.5f * a0);
  stage_T_f32(A, t0, Ts);
  for (int nt = 0; nt < 3; ++nt) {
    floatx4 acc[2][4];
    { floatx4 zv = {0.f, 0.f, 0.f, 0.f};
      #pragma unroll
      for (int i = 0; i < 2; ++i)
        #pragma unroll
        for (int j = 0; j < 4; ++j) acc[i][j] = zv; }
    for (int kt = 0; kt < 384; kt += 64) {
      __syncthreads();
      stage_W_f32(Bw, nt * 128, kt, Ws);
      __syncthreads();
      #pragma unroll
      for (int kc = 0; kc < 64; kc += 32) {
        FragAB af[2], bf[4];
        #pragma unroll
        for (int i = 0; i < 2; ++i) ldfragT(Ts, wm * 32 + i * 16 + l15, kt + kc + q * 8, af[i]);
        #pragma unroll
        for (int j = 0; j < 4; ++j) ldfragW(Ws, wn * 64 + j * 16 + l15, kc + q * 8, bf[j]);
        #pragma unroll
        for (int i = 0; i < 2; ++i)
          #pragma unroll
          for (int j = 0; j < 4; ++j)
            acc[i][j] = __builtin_amdgcn_mfma_f32_16x16x32_bf16(af[i].s, bf[j].s, acc[i][j], 0, 0, 0);
      }
    }
    #pragma unroll
    for (int i = 0; i < 2; ++i)
      #pragma unroll
      for (int j = 0; j < 4; ++j) {
        int ncol = nt * 128 + wn * 64 + j * 16 + l15;
        float bb = bias[ncol];
        #pragma unroll
        for (int r = 0; r < 4; ++r) {
          int t = t0 + wm * 32 + i * 16 + q * 4 + r;
          float v = acc[i][j][r] + bb;
          float tt = 0.5f * v * (1.0f + erff(v * 0.7071067811865476f));  // exact gelu
          float ct = c0 * tt;
          g[(size_t)t * 384 + ncol] = f2bf(cosf(ct) + sinf(ct) * sc);
        }
      }
  }
}

// GEMM3: out_w(fp32, A-operand) x A3(bf16 pixels, B-operand) -> d_out[b,c,h,w] fp32 + out_b
__global__ __launch_bounds__(256) void k_gemm_out(const float* __restrict__ Wo,
                                                  const u16* __restrict__ A3,
                                                  const float* __restrict__ bias,
                                                  float* __restrict__ outp) {
  __shared__ u16 Ts[64 * 384];   // pixel tile (B operand)
  __shared__ u16 Ws[128 * 64];   // out_w tile (A operand)
  const int tid = threadIdx.x, lane = tid & 63, wv = tid >> 6;
  const int wm = wv & 1, wn = wv >> 1, q = lane >> 4, l15 = lane & 15;
  const int t0 = blockIdx.x * 64;
  const int b = t0 / 3136, p0 = t0 - b * 3136;   // 64 | 3136 -> tile never crosses b
  stage_T_bf(A3, t0, Ts);
  for (int nt = 0; nt < 3; ++nt) {
    floatx4 acc[4][2];
    { floatx4 zv = {0.f, 0.f, 0.f, 0.f};
      #pragma unroll
      for (int i = 0; i < 4; ++i)
        #pragma unroll
        for (int j = 0; j < 2; ++j) acc[i][j] = zv; }
    for (int kt = 0; kt < 384; kt += 64) {
      __syncthreads();
      stage_W_f32(Wo, nt * 128, kt, Ws);
      __syncthreads();
      #pragma unroll
      for (int kc = 0; kc < 64; kc += 32) {
        FragAB af[4], bf[2];
        #pragma unroll
        for (int i = 0; i < 4; ++i) ldfragW(Ws, wm * 64 + i * 16 + l15, kc + q * 8, af[i]);
        #pragma unroll
        for (int j = 0; j < 2; ++j) ldfragT(Ts, wn * 32 + j * 16 + l15, kt + kc + q * 8, bf[j]);
        #pragma unroll
        for (int i = 0; i < 4; ++i)
          #pragma unroll
          for (int j = 0; j < 2; ++j)
            acc[i][j] = __builtin_amdgcn_mfma_f32_16x16x32_bf16(af[i].s, bf[j].s, acc[i][j], 0, 0, 0);
      }
    }
    #pragma unroll
    for (int i = 0; i < 4; ++i)
      #pragma unroll
      for (int j = 0; j < 2; ++j) {
        int pix = p0 + wn * 32 + j * 16 + l15;
        #pragma unroll
        for (int r = 0; r < 4; ++r) {
          int c = nt * 128 + wm * 64 + i * 16 + q * 4 + r;
          outp[((size_t)b * 384 + c) * 3136 + pix] = acc[i][j][r] + bias[c];
        }
      }
  }
}

// ---------------- DCT chain (fp32 math, bf16 storage, in-place) ----------------
__global__ __launch_bounds__(256) void k_dct_h(u16* __restrict__ xx,
                                               const float* __restrict__ Wd) {
  __shared__ float Xs[56 * 128];
  __shared__ float Ws[3136];
  const int w = blockIdx.x, cb = blockIdx.y * 128, b = blockIdx.z;
  const int tid = threadIdx.x;
  for (int i = tid; i < 3136; i += 256) Ws[i] = Wd[i];
  for (int i = tid; i < 56 * 64; i += 256) {
    int h = i >> 6, cu = i & 63;
    unsigned int p = *(const unsigned int*)(xx + ((size_t)(b * 56 + h) * 56 + w) * 384 + cb + cu * 2);
    bfp(p, Xs[h * 128 + cu * 2], Xs[h * 128 + cu * 2 + 1]);
  }
  __syncthreads();
  const int lane = tid & 63, wv = tid >> 6;
  float a0[14], a1[14];
  #pragma unroll
  for (int k = 0; k < 14; ++k) { a0[k] = 0.f; a1[k] = 0.f; }
  for (int h = 0; h < 56; ++h) {
    float x0 = Xs[h * 128 + 2 * lane];
    float x1 = Xs[h * 128 + 2 * lane + 1];
    #pragma unroll
    for (int k = 0; k < 14; ++k) {
      float wn = Ws[(wv + 4 * k) * 56 + h];
      a0[k] += wn * x0; a1[k] += wn * x1;
    }
  }
  #pragma unroll
  for (int k = 0; k < 14; ++k) {
    int n = wv + 4 * k;
    *(unsigned int*)(xx + ((size_t)(b * 56 + n) * 56 + w) * 384 + cb + 2 * lane) = packbf(a0[k], a1[k]);
  }
}

__global__ __launch_bounds__(256) void k_mid(u16* __restrict__ u1,
                                             const u16* __restrict__ g,
                                             const float* __restrict__ Wd) {
  __shared__ float Us[56 * 64];
  __shared__ float Vs[56 * 64];
  __shared__ float Ws[3136];
  const int n = blockIdx.x, cb = blockIdx.y * 64, b = blockIdx.z;
  const int tid = threadIdx.x;
  for (int i = tid; i < 3136; i += 256) Ws[i] = Wd[i];
  for (int i = tid; i < 56 * 32; i += 256) {
    int ww = i >> 5, cu = i & 31;
    unsigned int p = *(const unsigned int*)(u1 + ((size_t)(b * 56 + n) * 56 + ww) * 384 + cb + cu * 2);
    bfp(p, Us[ww * 64 + cu * 2], Us[ww * 64 + cu * 2 + 1]);
  }
  __syncthreads();
  const int lane = tid & 63, wv = tid >> 6;
  {
    float a[14];
    #pragma unroll
    for (int k = 0; k < 14; ++k) a[k] = 0.f;
    for (int ww = 0; ww < 56; ++ww) {
      float xv = Us[ww * 64 + lane];
      #pragma unroll
      for (int k = 0; k < 14; ++k)
        a[k] += Ws[(wv + 4 * k) * 56 + ww] * xv;
    }
    #pragma unroll
    for (int k = 0; k < 14; ++k) Vs[(wv + 4 * k) * 64 + lane] = a[k];
  }
  __syncthreads();
  for (int i = tid; i < 56 * 32; i += 256) {
    int m = i >> 5, cu = i & 31;
    unsigned int p = *(const unsigned int*)(g + ((size_t)(b * 56 + n) * 56 + m) * 384 + cb + cu * 2);
    float g0, g1; bfp(p, g0, g1);
    Vs[m * 64 + cu * 2]     *= g0;
    Vs[m * 64 + cu * 2 + 1] *= g1;
  }
  __syncthreads();
  {
    float a[14];
    #pragma unroll
    for (int k = 0; k < 14; ++k) a[k] = 0.f;
    for (int m = 0; m < 56; ++m) {
      float xv = Vs[m * 64 + lane];
      #pragma unroll
      for (int k = 0; k < 14; ++k)
        a[k] += Ws[m * 56 + (wv + 4 * k)] * xv;   // Wd[m, yy]
    }
    #pragma unroll
    for (int k = 0; k < 14; ++k) {
      int yy = wv + 4 * k;
      u1[((size_t)(b * 56 + n) * 56 + yy) * 384 + cb + lane] = f2bf(a[k]);
    }
  }
}

__global__ __launch_bounds__(256) void k_idct_h(u16* __restrict__ y1,
                                                const float* __restrict__ Wd) {
  __shared__ float Ys[56 * 128];
  __shared__ float Ws[3136];
  const int yy = blockIdx.x, cb = blockIdx.y * 128, b = blockIdx.z;
  const int tid = threadIdx.x;
  for (int i = tid; i < 3136; i += 256) Ws[i] = Wd[i];
  for (int i = tid; i < 56 * 64; i += 256) {
    int nn = i >> 6, cu = i & 63;
    unsigned int p = *(const unsigned int*)(y1 + ((size_t)(b * 56 + nn) * 56 + yy) * 384 + cb + cu * 2);
    bfp(p, Ys[nn * 128 + cu * 2], Ys[nn * 128 + cu * 2 + 1]);
  }
  __syncthreads();
  const int lane = tid & 63, wv = tid >> 6;
  float a0[14], a1[14];
  #pragma unroll
  for (int k = 0; k < 14; ++k) { a0[k] = 0.f; a1[k] = 0.f; }
  for (int nn = 0; nn < 56; ++nn) {
    float x0 = Ys[nn * 128 + 2 * lane];
    float x1 = Ys[nn * 128 + 2 * lane + 1];
    #pragma unroll
    for (int k = 0; k < 14; ++k) {
      float wn = Ws[nn * 56 + (wv + 4 * k)];   // Wd[n, x]
      a0[k] += wn * x0; a1[k] += wn * x1;
    }
  }
  #pragma unroll
  for (int k = 0; k < 14; ++k) {
    int x = wv + 4 * k;
    *(unsigned int*)(y1 + ((size_t)(b * 56 + x) * 56 + yy) * 384 + cb + 2 * lane) = packbf(a0[k], a1[k]);
  }
}

// ---------------- LayerNorm + SiLU gate -> bf16 A3 (in-place over y2) ----------------
__global__ __launch_bounds__(256) void k_ln(u16* __restrict__ y2,
                                            const u16* __restrict__ z,
                                            const float* __restrict__ lgm,
                                            const float* __restrict__ lbt) {
  const int t = blockIdx.x * 4 + (threadIdx.x >> 6);
  const int lane = threadIdx.x & 63;
  u16* yr = y2 + (size_t)t * 384;
  const u16* zr = z + (size_t)t * 384;
  float v[6]; float s = 0.f, s2 = 0.f;
  #pragma unroll
  for (int k = 0; k < 3; ++k) {
    unsigned int p = *(const unsigned int*)(yr + 2 * lane + 128 * k);
    float f0, f1; bfp(p, f0, f1);
    v[2 * k] = f0; v[2 * k + 1] = f1;
    s += f0 + f1; s2 += f0 * f0 + f1 * f1;
  }
  #pragma unroll
  for (int off = 32; off >= 1; off >>= 1) {
    s  += __shfl_xor(s, off, 64);
    s2 += __shfl_xor(s2, off, 64);
  }
  const float mu  = s * (1.0f / 384.0f);
  const float var = s2 * (1.0f / 384.0f) - mu * mu;
  const float inv = rsqrtf(var + 1e-5f);
  #pragma unroll
  for (int k = 0; k < 3; ++k) {
    int c = 2 * lane + 128 * k;
    float z0, z1;
    bfp(*(const unsigned int*)(zr + c), z0, z1);
    float yn0 = (v[2 * k]     - mu) * inv * lgm[c]     + lbt[c];
    float yn1 = (v[2 * k + 1] - mu) * inv * lgm[c + 1] + lbt[c + 1];
    float ga0 = z0 / (1.0f + expf(-z0));
    float ga1 = z1 / (1.0f + expf(-z1));
    *(unsigned int*)(yr + c) = packbf(yn0 * ga0, yn1 * ga1);
  }
}

// ---------------- launch ----------------
extern "C" void kernel_launch(void* const* d_in, const int* in_sizes, int n_in,
                              void* d_out, int out_size, void* d_ws, size_t ws_size,
                              hipStream_t stream) {
  const float* x     = (const float*)d_in[0];
  const float* fe    = (const float*)d_in[1];
  const float* dw_w  = (const float*)d_in[2];
  const float* dw_b  = (const float*)d_in[3];
  const float* lin_w = (const float*)d_in[4];
  const float* lin_b = (const float*)d_in[5];
  const float* tok_w = (const float*)d_in[6];
  const float* tok_b = (const float*)d_in[7];
  const float* ln_g  = (const float*)d_in[8];
  const float* ln_b  = (const float*)d_in[9];
  const float* out_w = (const float*)d_in[10];
  const float* out_b = (const float*)d_in[11];
  const float* cs    = (const float*)d_in[12];
  const float* al    = (const float*)d_in[13];
  float* outp = (float*)d_out;
  char* ws = (char*)d_ws;

  float* Wd = (float*)(ws + 0);                        // 12,544 B
  u16* SA = (u16*)(ws + 16384);                        // h, then g
  u16* SB = (u16*)(ws + 16384 + 38535168);             // xx -> u1 -> y1 -> y2 -> A3 (in-place chain)
  u16* SC = (u16*)(ws + 16384 + 2 * (size_t)38535168); // z

  k_dctmat<<<dim3(13), dim3(256), 0, stream>>>(Wd);
  k_conv<<<dim3(56, 6, 16), dim3(256), 0, stream>>>(x, dw_w, dw_b, SA);          // h in SA
  k_gemm_lin<<<dim3(784), dim3(256), 0, stream>>>(SA, lin_w, lin_b, SB, SC);     // xx in SB, z in SC
  k_gemm_tok<<<dim3(784), dim3(256), 0, stream>>>(fe, tok_w, tok_b, cs, al, SA); // g in SA
  k_dct_h<<<dim3(56, 3, 16), dim3(256), 0, stream>>>(SB, Wd);                    // xx -> u1
  k_mid<<<dim3(56, 6, 16), dim3(256), 0, stream>>>(SB, SA, Wd);                  // u1,g -> y1
  k_idct_h<<<dim3(56, 3, 16), dim3(256), 0, stream>>>(SB, Wd);                   // y1 -> y2
  k_ln<<<dim3(12544), dim3(256), 0, stream>>>(SB, SC, ln_g, ln_b);               // y2,z -> A3
  k_gemm_out<<<dim3(784), dim3(256), 0, stream>>>(out_w, SB, out_b, outp);
}